// Round 10
// baseline (322.649 us; speedup 1.0000x reference)
//
#include <hip/hip_runtime.h>
#include <hip/hip_fp16.h>

// GCN 2-layer forward (round-21: hist+scan eliminated via global bucket cursors):
//  K1 : W1 -> fp16^T swizzled (32 blocks) || zero bucket counters (1 block)
//  K2 : bucket scatter via atomicAdd(bcnt[bucket]) into fixed slabs (512 blocks)
//       || gemm1 via MFMA (782 blocks) -> g1
//  K3 : per-bucket CSR finalize (scan of bcnt -> row_ptr/dinv/esrc) + g1 pre-scale
//  K4 : aggregate1, 32-node tiles -> relu -> gemm2 (W2 via L1) -> g2 (pre-scaled)
//  K5 : aggregate2, 32-node tiles -> d_out

#define C_HID 64
#define NCHUNK 512
#define CAP 1536   // ebuf slab per 64-node bucket (mean 1023, sd 32 -> 16 sigma)
#define ES3 768    // LDS esrc capacity for 32-node tiles (mean 512, sd 23)
#define ES4 768

static inline size_t alignup(size_t x) { return (x + 255) & ~(size_t)255; }

typedef __attribute__((address_space(3))) unsigned int lds_uint;
typedef __attribute__((address_space(1))) const unsigned int glob_uint;
typedef __attribute__((ext_vector_type(4))) _Float16 half4;
typedef __attribute__((ext_vector_type(4))) float floatx4;

// ---- block-wide inclusive scan over 256 threads ----
__device__ __forceinline__ int blockScanIncl256(int v, int* wsum) {
    const int lane = threadIdx.x & 63, wav = threadIdx.x >> 6;
    int s = v;
#pragma unroll
    for (int off = 1; off < 64; off <<= 1) {
        int t = __shfl_up(s, off);
        if (lane >= off) s += t;
    }
    if (lane == 63) wsum[wav] = s;
    __syncthreads();
    if (wav == 0 && lane < 4) {
        int ws = wsum[lane];
#pragma unroll
        for (int off = 1; off < 4; off <<= 1) {
            int t = __shfl_up(ws, off);
            if (lane >= off) ws += t;
        }
        wsum[lane] = ws;
    }
    __syncthreads();
    return (wav ? wsum[wav - 1] : 0) + s;
}

// ================= K1: W1 cvt (blocks 0..31) || zero bcnt (block 32) ===============
// cvt: Wh[c*128 + (k ^ ((c&7)<<3))] = W1[k*64 + c]  (swizzle undone at ds_read)
__global__ __launch_bounds__(256) void cvt_zero_kernel(
    const float* __restrict__ W, __half* __restrict__ Wh,
    int* __restrict__ bcnt, int nb) {
    const int t = threadIdx.x;
    if ((int)blockIdx.x == 32) {
        for (int i = t; i < nb; i += 256) bcnt[i] = 0;
        return;
    }
    int i = (int)blockIdx.x * 256 + t;
    if (i < 64 * 128) {
        int c = i >> 7, k = i & 127;
        int ks = k ^ ((c & 7) << 3);
        Wh[c * 128 + ks] = __float2half(W[k * 64 + c]);
    }
}

// ================= K2: scatter via global cursors (blocks < NCHUNK) || gemm1 ========
template <int K>
__global__ __launch_bounds__(256) void scatter_gemm1_kernel(
    const int* __restrict__ src, const int* __restrict__ dst, int E, int ePer,
    int* __restrict__ bcnt, unsigned* __restrict__ ebuf,
    const float* __restrict__ X, const __half* __restrict__ Wh,
    __half* __restrict__ outh, int n) {
    constexpr int XP = K + 8;
    __shared__ __half Xs[64 * XP];     // 17408 B
    __shared__ __half WsT[64 * K];     // 16384 B   (gemm branch only)
    const int t = threadIdx.x;
    const int lane = t & 63;
    const int wav = t >> 6;

    if ((int)blockIdx.x < NCHUNK) {
        // ---- scatter branch: slab-append via global atomic bucket cursors ----
        int beg = blockIdx.x * ePer, end = min(E, beg + ePer);
        for (int e = beg + t; e < end; e += 256) {
            int d = dst[e];
            int s = src[e];
            int b = d >> 6;
            int pos = atomicAdd(&bcnt[b], 1);
            if (pos < CAP)
                ebuf[(size_t)b * CAP + pos] = ((unsigned)s << 6) | (unsigned)(d & 63);
        }
        return;
    }

    // ---- gemm1 branch (MFMA) ----
    const int row0 = ((int)blockIdx.x - NCHUNK) * 64;
    {   // W1h (fp16, 16KB, pre-swizzled) -> LDS via async DMA (linear dest)
        const char* gb = (const char*)Wh;
        char* lb = (char*)WsT;
        for (int off = wav * 1024; off < K * 64 * 2; off += 4096)
            __builtin_amdgcn_global_load_lds((glob_uint*)(gb + off + lane * 16),
                                             (lds_uint*)(lb + off), 16, 0, 0);
    }
    if (row0 + 64 <= n) {
        const float4* g4 = (const float4*)(X + (size_t)row0 * K);
        for (int i = t; i < 64 * (K / 4); i += 256) {
            float4 v = g4[i];
            int r = i / (K / 4), k0 = (i % (K / 4)) * 4;
            float2 st;
            ((__half2*)&st)[0] = __floats2half2_rn(v.x, v.y);
            ((__half2*)&st)[1] = __floats2half2_rn(v.z, v.w);
            *(float2*)&Xs[r * XP + k0] = st;
        }
    } else {
        for (int i = t; i < 64 * K; i += 256) {
            int r = i / K, k = i % K;
            float xv = (row0 + r < n) ? X[(size_t)(row0 + r) * K + k] : 0.0f;
            Xs[r * XP + k] = __float2half(xv);
        }
    }
    __syncthreads();

    // 16x16x16 f16 layouts: A row=l&15, k=(l>>4)*4+i; B col=l&15 same k;
    // D col=l&15, row=(l>>4)*4+reg.
    const int rl = lane & 15;
    const int kq = lane >> 4;
    floatx4 acc0 = {0.f, 0.f, 0.f, 0.f};
    floatx4 acc1 = {0.f, 0.f, 0.f, 0.f};
    floatx4 acc2 = {0.f, 0.f, 0.f, 0.f};
    floatx4 acc3 = {0.f, 0.f, 0.f, 0.f};
    const __half* xrow = &Xs[(wav * 16 + rl) * XP];
#pragma unroll
    for (int kb = 0; kb < K / 16; ++kb) {
        const int ka = kb * 16 + kq * 4;
        half4 a = *(const half4*)&xrow[ka];
        {   int col = 0 * 16 + rl;
            half4 b = *(const half4*)&WsT[col * K + (ka ^ ((col & 7) << 3))];
            acc0 = __builtin_amdgcn_mfma_f32_16x16x16f16(a, b, acc0, 0, 0, 0); }
        {   int col = 1 * 16 + rl;
            half4 b = *(const half4*)&WsT[col * K + (ka ^ ((col & 7) << 3))];
            acc1 = __builtin_amdgcn_mfma_f32_16x16x16f16(a, b, acc1, 0, 0, 0); }
        {   int col = 2 * 16 + rl;
            half4 b = *(const half4*)&WsT[col * K + (ka ^ ((col & 7) << 3))];
            acc2 = __builtin_amdgcn_mfma_f32_16x16x16f16(a, b, acc2, 0, 0, 0); }
        {   int col = 3 * 16 + rl;
            half4 b = *(const half4*)&WsT[col * K + (ka ^ ((col & 7) << 3))];
            acc3 = __builtin_amdgcn_mfma_f32_16x16x16f16(a, b, acc3, 0, 0, 0); }
    }
#pragma unroll
    for (int r = 0; r < 4; ++r) {
        int row = row0 + wav * 16 + kq * 4 + r;
        if (row < n) {
            __half* orow = &outh[(size_t)row * 64];
            orow[0 * 16 + rl] = __float2half(acc0[r]);
            orow[1 * 16 + rl] = __float2half(acc1[r]);
            orow[2 * 16 + rl] = __float2half(acc2[r]);
            orow[3 * 16 + rl] = __float2half(acc3[r]);
        }
    }
}

// ================= K3: per-bucket CSR finalize + g1 pre-scale by dinv ===============
__global__ __launch_bounds__(256) void build_kernel(
    const unsigned* __restrict__ ebuf, const int* __restrict__ bcnt,
    int* __restrict__ row_ptr, float* __restrict__ dinv,
    int* __restrict__ esrc, __half* __restrict__ g1, int n, int nb) {
    __shared__ int tmp[1024];
    __shared__ int cnt[64];
    __shared__ int cur[64];
    __shared__ float dvs[64];
    __shared__ int wsum[4];
    const int b = blockIdx.x, t = threadIdx.x;
    {   // in-block redundant scan of bucket counts -> global edge offsets
        int a0 = (4 * t + 0 < nb) ? min(bcnt[4 * t + 0], CAP) : 0;
        int a1 = (4 * t + 1 < nb) ? min(bcnt[4 * t + 1], CAP) : 0;
        int a2 = (4 * t + 2 < nb) ? min(bcnt[4 * t + 2], CAP) : 0;
        int a3 = (4 * t + 3 < nb) ? min(bcnt[4 * t + 3], CAP) : 0;
        int p1 = a0 + a1, p2 = p1 + a2, p3 = p2 + a3;
        int incl = blockScanIncl256(p3, wsum);
        int excl = incl - p3;
        tmp[4 * t + 0] = excl + a0;       // inclusive scan
        tmp[4 * t + 1] = excl + p1;
        tmp[4 * t + 2] = excl + p2;
        tmp[4 * t + 3] = excl + p3;
    }
    if (t < 64) cnt[t] = 0;
    __syncthreads();
    const int ebeg = b ? tmp[b - 1] : 0;
    const int cntb = tmp[b] - ebeg;
    const unsigned* slab = ebuf + (size_t)b * CAP;

    for (int e = t; e < cntb; e += 256)
        atomicAdd(&cnt[slab[e] & 63], 1);
    __syncthreads();
    if (t < 64) {
        int deg = cnt[t];
        int s = deg;
#pragma unroll
        for (int off = 1; off < 64; off <<= 1) {
            int x = __shfl_up(s, off);
            if (t >= off) s += x;
        }
        cur[t] = ebeg + s - deg;          // cursor = exclusive
        float dv = rsqrtf(1.0f + (float)deg);
        dvs[t] = dv;
        int v = (b << 6) + t;
        if (v < n) {
            row_ptr[v + 1] = ebeg + s;
            dinv[v] = dv;
            if (v == 0) row_ptr[0] = 0;
        }
    }
    __syncthreads();
    for (int e = t; e < cntb; e += 256) {
        unsigned p = slab[e];
        int pos = atomicAdd(&cur[p & 63], 1);            // LDS atomic
        esrc[pos] = (int)(p >> 6);
    }
    // epilogue: pre-scale this bucket's g1 rows by dinv (row = t>>2, quarter = t&3)
    {
        const int row = t >> 2, q = t & 3;
        const int v = (b << 6) + row;
        if (v < n) {
            float dv = dvs[row];
            float4* gp = (float4*)(g1 + (size_t)v * 64 + q * 16);
            float4 r0 = gp[0], r1 = gp[1];
            __half2* h0 = (__half2*)&r0;
            __half2* h1 = (__half2*)&r1;
#pragma unroll
            for (int i2 = 0; i2 < 4; ++i2) {
                float2 f0 = __half22float2(h0[i2]);
                float2 f1 = __half22float2(h1[i2]);
                h0[i2] = __floats2half2_rn(f0.x * dv, f0.y * dv);
                h1[i2] = __floats2half2_rn(f1.x * dv, f1.y * dv);
            }
            gp[0] = r0;
            gp[1] = r1;
        }
    }
}

// ---- 8-lanes-per-node aggregation helpers (rows pre-scaled) ----
__device__ __forceinline__ void addf4(float acc[8], const float4& r) {
    const __half2* h = (const __half2*)&r;
#pragma unroll
    for (int q = 0; q < 4; ++q) {
        float2 f = __half22float2(h[q]);
        acc[2 * q] += f.x;
        acc[2 * q + 1] += f.y;
    }
}

template <bool LDSE>
__device__ __forceinline__ void agg8_body(
    const float4* __restrict__ hs4, const int* es, const int* __restrict__ esg,
    int beg0, int beg, int end, int c8, float acc[8]) {
    int j = beg;
    for (; j + 8 <= end; j += 8) {          // 8 loads in flight
        int s0, s1, s2, s3, s4, s5, s6, s7;
        if (LDSE) {
            s0 = es[j];     s1 = es[j + 1]; s2 = es[j + 2]; s3 = es[j + 3];
            s4 = es[j + 4]; s5 = es[j + 5]; s6 = es[j + 6]; s7 = es[j + 7];
        } else {
            const int* p = esg + beg0 + j;
            s0 = p[0]; s1 = p[1]; s2 = p[2]; s3 = p[3];
            s4 = p[4]; s5 = p[5]; s6 = p[6]; s7 = p[7];
        }
        float4 r0 = hs4[(size_t)s0 * 8 + c8];
        float4 r1 = hs4[(size_t)s1 * 8 + c8];
        float4 r2 = hs4[(size_t)s2 * 8 + c8];
        float4 r3 = hs4[(size_t)s3 * 8 + c8];
        float4 r4 = hs4[(size_t)s4 * 8 + c8];
        float4 r5 = hs4[(size_t)s5 * 8 + c8];
        float4 r6 = hs4[(size_t)s6 * 8 + c8];
        float4 r7 = hs4[(size_t)s7 * 8 + c8];
        addf4(acc, r0); addf4(acc, r1); addf4(acc, r2); addf4(acc, r3);
        addf4(acc, r4); addf4(acc, r5); addf4(acc, r6); addf4(acc, r7);
    }
    if (j + 4 <= end) {                      // unroll-4 middle
        int s0, s1, s2, s3;
        if (LDSE) {
            s0 = es[j]; s1 = es[j + 1]; s2 = es[j + 2]; s3 = es[j + 3];
        } else {
            const int* p = esg + beg0 + j;
            s0 = p[0]; s1 = p[1]; s2 = p[2]; s3 = p[3];
        }
        float4 r0 = hs4[(size_t)s0 * 8 + c8];
        float4 r1 = hs4[(size_t)s1 * 8 + c8];
        float4 r2 = hs4[(size_t)s2 * 8 + c8];
        float4 r3 = hs4[(size_t)s3 * 8 + c8];
        addf4(acc, r0); addf4(acc, r1); addf4(acc, r2); addf4(acc, r3);
        j += 4;
    }
    for (; j < end; ++j) {                   // <=3 singles
        int s0 = LDSE ? es[j] : esg[beg0 + j];
        float4 r0 = hs4[(size_t)s0 * 8 + c8];
        addf4(acc, r0);
    }
}

// ================= K4: aggregate layer1 + gemm2 (fused), 32-node tiles ==============
// LDS = Bt + es only (11.8KB -> 8 blk/CU); W2 read from global (L1-resident 16KB).
__global__ __launch_bounds__(256) void agg1_gemm2_kernel(
    const __half* __restrict__ g1, const int* __restrict__ row_ptr,
    const int* __restrict__ esrc, const float* __restrict__ dinv,
    const float* __restrict__ b1, const float* __restrict__ W2,
    __half* __restrict__ g2, int n) {
    __shared__ float Bt[32][68];      // 8704 B
    __shared__ int es[ES3];           // 3072 B  -> 11776 B total
    const int t = threadIdx.x;
    const int row0 = blockIdx.x * 32;

    const int beg0 = row_ptr[row0];
    const int end0 = row_ptr[min(row0 + 32, n)];
    const int tot = end0 - beg0;
    const bool uselds = (tot <= ES3);
    if (uselds)
        for (int i = t; i < tot; i += 256) es[i] = esrc[beg0 + i];
    __syncthreads();

    const int g = t >> 3;        // node in tile (0..31)
    const int c8 = t & 7;        // float4 slot in row
    const int v = row0 + g;
    const float4* __restrict__ hs4 = (const float4*)g1;

    if (v < n) {
        float acc[8];
        {   // self term (g1 pre-scaled by dinv[v])
            float4 raw = hs4[(size_t)v * 8 + c8];
            const __half2* hp = (const __half2*)&raw;
#pragma unroll
            for (int q = 0; q < 4; ++q) {
                float2 f = __half22float2(hp[q]);
                acc[2 * q] = f.x; acc[2 * q + 1] = f.y;
            }
        }
        const int beg = row_ptr[v] - beg0;
        const int end = row_ptr[v + 1] - beg0;
        if (uselds) agg8_body<true>(hs4, es, esrc, beg0, beg, end, c8, acc);
        else        agg8_body<false>(hs4, es, esrc, beg0, beg, end, c8, acc);
        const float dv0 = dinv[v];
        const float* bb = b1 + c8 * 8;
        float4 w0, w1;
        w0.x = fmaxf(fmaf(acc[0], dv0, bb[0]), 0.f);
        w0.y = fmaxf(fmaf(acc[1], dv0, bb[1]), 0.f);
        w0.z = fmaxf(fmaf(acc[2], dv0, bb[2]), 0.f);
        w0.w = fmaxf(fmaf(acc[3], dv0, bb[3]), 0.f);
        w1.x = fmaxf(fmaf(acc[4], dv0, bb[4]), 0.f);
        w1.y = fmaxf(fmaf(acc[5], dv0, bb[5]), 0.f);
        w1.z = fmaxf(fmaf(acc[6], dv0, bb[6]), 0.f);
        w1.w = fmaxf(fmaf(acc[7], dv0, bb[7]), 0.f);
        *(float4*)&Bt[g][c8 * 8] = w0;
        *(float4*)&Bt[g][c8 * 8 + 4] = w1;
    } else {
        *(float4*)&Bt[g][c8 * 8] = make_float4(0.f, 0.f, 0.f, 0.f);
        *(float4*)&Bt[g][c8 * 8 + 4] = make_float4(0.f, 0.f, 0.f, 0.f);
    }
    __syncthreads();

    // gemm2: [32 x 64] @ [64 x 64]; each thread 2 rows x 4 cols; W2 via L1
    const int tx = t & 15;
    const int ty = t >> 4;
    float a2[2][4] = {{0.f}};
#pragma unroll 2
    for (int k0 = 0; k0 < 64; k0 += 4) {
        float4 x0 = *(const float4*)&Bt[2 * ty + 0][k0];
        float4 x1 = *(const float4*)&Bt[2 * ty + 1][k0];
        float4 w0 = *(const float4*)&W2[(k0 + 0) * 64 + 4 * tx];
        float4 w1 = *(const float4*)&W2[(k0 + 1) * 64 + 4 * tx];
        float4 w2 = *(const float4*)&W2[(k0 + 2) * 64 + 4 * tx];
        float4 w3 = *(const float4*)&W2[(k0 + 3) * 64 + 4 * tx];
        const float* xp[2] = {(const float*)&x0, (const float*)&x1};
        const float* wp[4] = {(const float*)&w0, (const float*)&w1,
                              (const float*)&w2, (const float*)&w3};
#pragma unroll
        for (int r = 0; r < 2; ++r)
#pragma unroll
            for (int kk = 0; kk < 4; ++kk) {
                float av = xp[r][kk];
#pragma unroll
                for (int cc = 0; cc < 4; ++cc)
                    a2[r][cc] = fmaf(av, wp[kk][cc], a2[r][cc]);
            }
    }
#pragma unroll
    for (int r = 0; r < 2; ++r) {
        int row = row0 + 2 * ty + r;
        if (row < n) {
            float dv = dinv[row];
            __half2 p01 = __floats2half2_rn(a2[r][0] * dv, a2[r][1] * dv);
            __half2 p23 = __floats2half2_rn(a2[r][2] * dv, a2[r][3] * dv);
            float2 st;
            ((__half2*)&st)[0] = p01;
            ((__half2*)&st)[1] = p23;
            *(float2*)&g2[(size_t)row * 64 + 4 * tx] = st;
        }
    }
}

// ================= K5: aggregate layer2 -> d_out =================
__global__ __launch_bounds__(256) void aggregate2_kernel(
    const __half* __restrict__ hs,
    const int* __restrict__ row_ptr,
    const int* __restrict__ esrc,
    const float* __restrict__ dinv,
    const float* __restrict__ bias,
    float* __restrict__ out, int n) {
    __shared__ int es[ES4];
    const int t = threadIdx.x;
    const int row0 = blockIdx.x * 32;
    const int beg0 = row_ptr[row0];
    const int end0 = row_ptr[min(row0 + 32, n)];
    const int tot = end0 - beg0;
    const bool uselds = (tot <= ES4);
    if (uselds)
        for (int i = t; i < tot; i += 256) es[i] = esrc[beg0 + i];
    __syncthreads();

    const int v = row0 + (t >> 3);
    if (v >= n) return;
    const int c8 = t & 7;
    const float4* __restrict__ hs4 = (const float4*)hs;

    float acc[8];
    {   // self term (g2 pre-scaled)
        float4 raw = hs4[(size_t)v * 8 + c8];
        const __half2* hp = (const __half2*)&raw;
#pragma unroll
        for (int q = 0; q < 4; ++q) {
            float2 f = __half22float2(hp[q]);
            acc[2 * q] = f.x; acc[2 * q + 1] = f.y;
        }
    }

    const int beg = row_ptr[v] - beg0;
    const int end = row_ptr[v + 1] - beg0;
    if (uselds) agg8_body<true>(hs4, es, esrc, beg0, beg, end, c8, acc);
    else        agg8_body<false>(hs4, es, esrc, beg0, beg, end, c8, acc);

    float dv = dinv[v];
    float4 b0 = *(const float4*)(bias + c8 * 8);
    float4 b1v = *(const float4*)(bias + c8 * 8 + 4);
    float4 o0, o1;
    o0.x = fmaf(acc[0], dv, b0.x); o0.y = fmaf(acc[1], dv, b0.y);
    o0.z = fmaf(acc[2], dv, b0.z); o0.w = fmaf(acc[3], dv, b0.w);
    o1.x = fmaf(acc[4], dv, b1v.x); o1.y = fmaf(acc[5], dv, b1v.y);
    o1.z = fmaf(acc[6], dv, b1v.z); o1.w = fmaf(acc[7], dv, b1v.w);
    float4* op = (float4*)(out + (size_t)v * 64 + c8 * 8);
    op[0] = o0;
    op[1] = o1;
}

extern "C" void kernel_launch(void* const* d_in, const int* in_sizes, int n_in,
                              void* d_out, int out_size, void* d_ws, size_t ws_size,
                              hipStream_t stream) {
    const float* x  = (const float*)d_in[0];
    const int*   ei = (const int*)d_in[1];
    const float* W1 = (const float*)d_in[2];
    const float* b1 = (const float*)d_in[3];
    const float* W2 = (const float*)d_in[4];
    const float* b2 = (const float*)d_in[5];
    float* out = (float*)d_out;

    const int C_IN = 128;
    const int n = in_sizes[0] / C_IN;   // 50000 (<= 65536: nb <= 1024)
    const int E = in_sizes[1] / 2;      // 800000
    const int* src = ei;
    const int* dst = ei + E;

    const int nb = (n + 63) >> 6;               // 782 buckets of 64 nodes
    const int ngb = (n + 63) / 64;              // gemm1 tile blocks
    const int n32 = (n + 31) / 32;              // 32-node tiles for K4/K5
    const int ePer = (E + NCHUNK - 1) / NCHUNK; // edges per scatter chunk

    // Workspace: dinv | g1 | g2 | row_ptr | bcnt | ebuf slabs | esrc | W1h
    char* w = (char*)d_ws;
    float*    dinv    = (float*)w;    w += alignup((size_t)n * sizeof(float));
    __half*   g1      = (__half*)w;   w += alignup((size_t)n * C_HID * sizeof(__half));
    __half*   g2      = (__half*)w;   w += alignup((size_t)n * C_HID * sizeof(__half));
    int*      row_ptr = (int*)w;      w += alignup((size_t)(n + 1) * sizeof(int));
    int*      bcnt    = (int*)w;      w += alignup((size_t)nb * sizeof(int));
    unsigned* ebuf    = (unsigned*)w; w += alignup((size_t)nb * CAP * sizeof(unsigned));
    int*      esrc    = (int*)w;      w += alignup((size_t)E * sizeof(int));
    __half*   W1h     = (__half*)w;

    // K1: W1 cvt || zero bucket counters
    cvt_zero_kernel<<<33, 256, 0, stream>>>(W1, W1h, bcnt, nb);

    // K2: scatter (global bucket cursors) || gemm1 (MFMA)
    scatter_gemm1_kernel<128><<<NCHUNK + ngb, 256, 0, stream>>>(
        src, dst, E, ePer, bcnt, ebuf, x, W1h, g1, n);

    // K3: build (scan bcnt -> row_ptr/dinv/esrc) + g1 pre-scale
    build_kernel<<<nb, 256, 0, stream>>>(ebuf, bcnt, row_ptr, dinv, esrc, g1, n, nb);

    // K4: aggregate layer1 + gemm2 fused (32-node tiles, 8 blk/CU)
    agg1_gemm2_kernel<<<n32, 256, 0, stream>>>(
        g1, row_ptr, esrc, dinv, b1, W2, g2, n);

    // K5: aggregate layer2 -> out (32-node tiles)
    aggregate2_kernel<<<n32, 256, 0, stream>>>(
        g2, row_ptr, esrc, dinv, b2, out, n);
}

// Round 11
// 153.869 us; speedup vs baseline: 2.0969x; 2.0969x over previous
//
#include <hip/hip_runtime.h>
#include <hip/hip_fp16.h>

// GCN 2-layer forward (round-22 = revert to round-18/round-7 best, 156.28us):
//  K0 : cvt W1 -> fp16, transposed [col][k], XOR swizzle baked into global layout
//  K1 : gemm1 via v_mfma_f32_16x16x16_f16 (fp16 LDS tiles) || edge histogram -> S
//  K2a: per-bucket row scan of S -> T totals
//  K2b: bucket scatter (512 chunks, in-block redundant T scan)
//  K2c: per-bucket CSR finalize + g1 pre-scale by dinv
//  K3 : aggregate1, 32-node tiles / 8 lanes/node -> relu -> gemm2 -> g2 (pre-scaled)
//  K4 : aggregate2, 32-node tiles -> d_out

#define C_HID 64
#define NCHUNK 512
#define ES3 768    // LDS esrc capacity for 32-node tiles (mean 512, sd 23)
#define ES4 768

static inline size_t alignup(size_t x) { return (x + 255) & ~(size_t)255; }

typedef __attribute__((address_space(3))) unsigned int lds_uint;
typedef __attribute__((address_space(1))) const unsigned int glob_uint;
typedef __attribute__((ext_vector_type(4))) _Float16 half4;
typedef __attribute__((ext_vector_type(4))) float floatx4;

// ---- block-wide inclusive scan over 256 threads ----
__device__ __forceinline__ int blockScanIncl256(int v, int* wsum) {
    const int lane = threadIdx.x & 63, wav = threadIdx.x >> 6;
    int s = v;
#pragma unroll
    for (int off = 1; off < 64; off <<= 1) {
        int t = __shfl_up(s, off);
        if (lane >= off) s += t;
    }
    if (lane == 63) wsum[wav] = s;
    __syncthreads();
    if (wav == 0 && lane < 4) {
        int ws = wsum[lane];
#pragma unroll
        for (int off = 1; off < 4; off <<= 1) {
            int t = __shfl_up(ws, off);
            if (lane >= off) ws += t;
        }
        wsum[lane] = ws;
    }
    __syncthreads();
    return (wav ? wsum[wav - 1] : 0) + s;
}

// ================= K0: W1 -> fp16 transposed+swizzled =================
// Wh[c*128 + (k ^ ((c&7)<<3))] = W1[k*64 + c]; DMA to LDS stays linear,
// the swizzle is undone at ds_read time (both-sides rule).
__global__ __launch_bounds__(256) void cvt_w1t_kernel(
    const float* __restrict__ W, __half* __restrict__ Wh) {
    int i = blockIdx.x * 256 + threadIdx.x;
    if (i < 64 * 128) {
        int c = i >> 7, k = i & 127;
        int ks = k ^ ((c & 7) << 3);
        Wh[c * 128 + ks] = __float2half(W[k * 64 + c]);
    }
}

// ================= K1: gemm1 (MFMA) || hist =================
template <int K>
__global__ __launch_bounds__(256) void gemm1_hist_kernel(
    const float* __restrict__ X, const __half* __restrict__ Wh,
    const int* __restrict__ dst, __half* __restrict__ outh,
    int* __restrict__ S, int n, int E, int ePer, int nb) {
    constexpr int XP = K + 8;          // pad: 2-way LDS conflicts only
    __shared__ __half Xs[64 * XP];     // 17408 B
    __shared__ __half WsT[64 * K];     // 16384 B (swizzled [col][k])
    __shared__ int h[1024];            //  4096 B  -> ~37.9KB, 4 blk/CU
    const int t = threadIdx.x;
    const int lane = t & 63;
    const int wav = t >> 6;

    if ((int)blockIdx.x < NCHUNK) {
        for (int i = t; i < nb; i += 256) h[i] = 0;
        __syncthreads();
        int beg = blockIdx.x * ePer, end = min(E, beg + ePer);
        for (int e = beg + t; e < end; e += 256)
            atomicAdd(&h[dst[e] >> 6], 1);
        __syncthreads();
        for (int b = t; b < nb; b += 256)
            S[(size_t)b * NCHUNK + blockIdx.x] = h[b];
        return;
    }

    const int row0 = ((int)blockIdx.x - NCHUNK) * 64;
    {   // W1h (fp16, 16KB, pre-swizzled) -> LDS via async DMA (linear dest)
        const char* gb = (const char*)Wh;
        char* lb = (char*)WsT;
        for (int off = wav * 1024; off < K * 64 * 2; off += 4096)
            __builtin_amdgcn_global_load_lds((glob_uint*)(gb + off + lane * 16),
                                             (lds_uint*)(lb + off), 16, 0, 0);
    }
    if (row0 + 64 <= n) {
        const float4* g4 = (const float4*)(X + (size_t)row0 * K);
        for (int i = t; i < 64 * (K / 4); i += 256) {
            float4 v = g4[i];
            int r = i / (K / 4), k0 = (i % (K / 4)) * 4;
            float2 st;
            ((__half2*)&st)[0] = __floats2half2_rn(v.x, v.y);
            ((__half2*)&st)[1] = __floats2half2_rn(v.z, v.w);
            *(float2*)&Xs[r * XP + k0] = st;
        }
    } else {
        for (int i = t; i < 64 * K; i += 256) {
            int r = i / K, k = i % K;
            float xv = (row0 + r < n) ? X[(size_t)(row0 + r) * K + k] : 0.0f;
            Xs[r * XP + k] = __float2half(xv);
        }
    }
    __syncthreads();

    // MFMA: wave w computes rows [w*16, w*16+16) x all 64 cols.
    // 16x16x16 f16 layouts: A row=l&15, k=(l>>4)*4+i; B col=l&15, same k;
    // D col=l&15, row=(l>>4)*4+reg.
    const int rl = lane & 15;
    const int kq = lane >> 4;
    floatx4 acc0 = {0.f, 0.f, 0.f, 0.f};
    floatx4 acc1 = {0.f, 0.f, 0.f, 0.f};
    floatx4 acc2 = {0.f, 0.f, 0.f, 0.f};
    floatx4 acc3 = {0.f, 0.f, 0.f, 0.f};
    const __half* xrow = &Xs[(wav * 16 + rl) * XP];
#pragma unroll
    for (int kb = 0; kb < K / 16; ++kb) {
        const int ka = kb * 16 + kq * 4;
        half4 a = *(const half4*)&xrow[ka];
        {   int col = 0 * 16 + rl;
            half4 b = *(const half4*)&WsT[col * K + (ka ^ ((col & 7) << 3))];
            acc0 = __builtin_amdgcn_mfma_f32_16x16x16f16(a, b, acc0, 0, 0, 0); }
        {   int col = 1 * 16 + rl;
            half4 b = *(const half4*)&WsT[col * K + (ka ^ ((col & 7) << 3))];
            acc1 = __builtin_amdgcn_mfma_f32_16x16x16f16(a, b, acc1, 0, 0, 0); }
        {   int col = 2 * 16 + rl;
            half4 b = *(const half4*)&WsT[col * K + (ka ^ ((col & 7) << 3))];
            acc2 = __builtin_amdgcn_mfma_f32_16x16x16f16(a, b, acc2, 0, 0, 0); }
        {   int col = 3 * 16 + rl;
            half4 b = *(const half4*)&WsT[col * K + (ka ^ ((col & 7) << 3))];
            acc3 = __builtin_amdgcn_mfma_f32_16x16x16f16(a, b, acc3, 0, 0, 0); }
    }
#pragma unroll
    for (int r = 0; r < 4; ++r) {
        int row = row0 + wav * 16 + kq * 4 + r;
        if (row < n) {
            __half* orow = &outh[(size_t)row * 64];
            orow[0 * 16 + rl] = __float2half(acc0[r]);
            orow[1 * 16 + rl] = __float2half(acc1[r]);
            orow[2 * 16 + rl] = __float2half(acc2[r]);
            orow[3 * 16 + rl] = __float2half(acc3[r]);
        }
    }
}

// ================= K2a: exclusive scan of each bucket-row of S; T[b] = row total ====
__global__ __launch_bounds__(256) void scan_rows_kernel(
    int* __restrict__ S, int* __restrict__ T) {
    __shared__ int wsum[4];
    const int b = blockIdx.x, t = threadIdx.x;
    int4 v = make_int4(0, 0, 0, 0);
    if (t < NCHUNK / 4) v = ((const int4*)(S + (size_t)b * NCHUNK))[t];
    int p1 = v.x + v.y, p2 = p1 + v.z, p3 = p2 + v.w;
    int incl = blockScanIncl256(p3, wsum);
    int excl = incl - p3;
    if (t < NCHUNK / 4) {
        int4 o;
        o.x = excl; o.y = excl + v.x; o.z = excl + p1; o.w = excl + p2;
        ((int4*)(S + (size_t)b * NCHUNK))[t] = o;
    }
    if (t == 0) T[b] = wsum[3];
}

// ================= K2b: bucket scatter (512 chunks; redundant in-block T scan) ======
__global__ __launch_bounds__(256) void scatter_kernel(
    const int* __restrict__ src, const int* __restrict__ dst, int E, int ePer,
    const int* __restrict__ S, const int* __restrict__ T,
    unsigned* __restrict__ ebuf, int nb) {
    __shared__ int tmp[1024];
    __shared__ int arr[1024];
    __shared__ int wsum[4];
    const int b = blockIdx.x, t = threadIdx.x;
    {
        int a0 = (4 * t + 0 < nb) ? T[4 * t + 0] : 0;
        int a1 = (4 * t + 1 < nb) ? T[4 * t + 1] : 0;
        int a2 = (4 * t + 2 < nb) ? T[4 * t + 2] : 0;
        int a3 = (4 * t + 3 < nb) ? T[4 * t + 3] : 0;
        int p1 = a0 + a1, p2 = p1 + a2, p3 = p2 + a3;
        int incl = blockScanIncl256(p3, wsum);
        int excl = incl - p3;
        tmp[4 * t + 0] = excl;            // exclusive totals scan
        tmp[4 * t + 1] = excl + a0;
        tmp[4 * t + 2] = excl + p1;
        tmp[4 * t + 3] = excl + p2;
    }
    __syncthreads();
    for (int i = t; i < nb; i += 256)
        arr[i] = S[(size_t)i * NCHUNK + b] + tmp[i];
    __syncthreads();
    int beg = b * ePer, end = min(E, beg + ePer);
    for (int e = beg + t; e < end; e += 256) {
        int d = dst[e];
        int s = src[e];
        int pos = atomicAdd(&arr[d >> 6], 1);            // LDS atomic
        ebuf[pos] = ((unsigned)s << 6) | (unsigned)(d & 63);
    }
}

// ================= K2c: per-bucket CSR finalize + g1 pre-scale by dinv ==============
__global__ __launch_bounds__(256) void build_kernel(
    const unsigned* __restrict__ ebuf, const int* __restrict__ T,
    int* __restrict__ row_ptr, float* __restrict__ dinv,
    int* __restrict__ esrc, __half* __restrict__ g1, int n, int nb) {
    __shared__ int tmp[1024];
    __shared__ int cnt[64];
    __shared__ int cur[64];
    __shared__ float dvs[64];
    __shared__ int wsum[4];
    const int b = blockIdx.x, t = threadIdx.x;
    {
        int a0 = (4 * t + 0 < nb) ? T[4 * t + 0] : 0;
        int a1 = (4 * t + 1 < nb) ? T[4 * t + 1] : 0;
        int a2 = (4 * t + 2 < nb) ? T[4 * t + 2] : 0;
        int a3 = (4 * t + 3 < nb) ? T[4 * t + 3] : 0;
        int p1 = a0 + a1, p2 = p1 + a2, p3 = p2 + a3;
        int incl = blockScanIncl256(p3, wsum);
        int excl = incl - p3;
        tmp[4 * t + 0] = excl + a0;       // inclusive totals scan
        tmp[4 * t + 1] = excl + p1;
        tmp[4 * t + 2] = excl + p2;
        tmp[4 * t + 3] = excl + p3;
    }
    if (t < 64) cnt[t] = 0;
    __syncthreads();
    const int ebeg = b ? tmp[b - 1] : 0;
    const int eend = tmp[b];

    for (int e = ebeg + t; e < eend; e += 256)
        atomicAdd(&cnt[ebuf[e] & 63], 1);
    __syncthreads();
    if (t < 64) {
        int deg = cnt[t];
        int s = deg;
#pragma unroll
        for (int off = 1; off < 64; off <<= 1) {
            int x = __shfl_up(s, off);
            if (t >= off) s += x;
        }
        cur[t] = ebeg + s - deg;          // cursor = exclusive
        float dv = rsqrtf(1.0f + (float)deg);
        dvs[t] = dv;
        int v = (b << 6) + t;
        if (v < n) {
            row_ptr[v + 1] = ebeg + s;
            dinv[v] = dv;
            if (v == 0) row_ptr[0] = 0;
        }
    }
    __syncthreads();
    for (int e = ebeg + t; e < eend; e += 256) {
        unsigned p = ebuf[e];
        int pos = atomicAdd(&cur[p & 63], 1);            // LDS atomic
        esrc[pos] = (int)(p >> 6);
    }
    // epilogue: pre-scale this bucket's g1 rows by dinv (row = t>>2, quarter = t&3)
    {
        const int row = t >> 2, q = t & 3;
        const int v = (b << 6) + row;
        if (v < n) {
            float dv = dvs[row];
            float4* gp = (float4*)(g1 + (size_t)v * 64 + q * 16);
            float4 r0 = gp[0], r1 = gp[1];
            __half2* h0 = (__half2*)&r0;
            __half2* h1 = (__half2*)&r1;
#pragma unroll
            for (int i2 = 0; i2 < 4; ++i2) {
                float2 f0 = __half22float2(h0[i2]);
                float2 f1 = __half22float2(h1[i2]);
                h0[i2] = __floats2half2_rn(f0.x * dv, f0.y * dv);
                h1[i2] = __floats2half2_rn(f1.x * dv, f1.y * dv);
            }
            gp[0] = r0;
            gp[1] = r1;
        }
    }
}

// ---- 8-lanes-per-node aggregation helpers (rows pre-scaled) ----
__device__ __forceinline__ void addf4(float acc[8], const float4& r) {
    const __half2* h = (const __half2*)&r;
#pragma unroll
    for (int q = 0; q < 4; ++q) {
        float2 f = __half22float2(h[q]);
        acc[2 * q] += f.x;
        acc[2 * q + 1] += f.y;
    }
}

template <bool LDSE>
__device__ __forceinline__ void agg8_body(
    const float4* __restrict__ hs4, const int* es, const int* __restrict__ esg,
    int beg0, int beg, int end, int c8, float acc[8]) {
    int j = beg;
    for (; j + 8 <= end; j += 8) {          // 8 loads in flight
        int s0, s1, s2, s3, s4, s5, s6, s7;
        if (LDSE) {
            s0 = es[j];     s1 = es[j + 1]; s2 = es[j + 2]; s3 = es[j + 3];
            s4 = es[j + 4]; s5 = es[j + 5]; s6 = es[j + 6]; s7 = es[j + 7];
        } else {
            const int* p = esg + beg0 + j;
            s0 = p[0]; s1 = p[1]; s2 = p[2]; s3 = p[3];
            s4 = p[4]; s5 = p[5]; s6 = p[6]; s7 = p[7];
        }
        float4 r0 = hs4[(size_t)s0 * 8 + c8];
        float4 r1 = hs4[(size_t)s1 * 8 + c8];
        float4 r2 = hs4[(size_t)s2 * 8 + c8];
        float4 r3 = hs4[(size_t)s3 * 8 + c8];
        float4 r4 = hs4[(size_t)s4 * 8 + c8];
        float4 r5 = hs4[(size_t)s5 * 8 + c8];
        float4 r6 = hs4[(size_t)s6 * 8 + c8];
        float4 r7 = hs4[(size_t)s7 * 8 + c8];
        addf4(acc, r0); addf4(acc, r1); addf4(acc, r2); addf4(acc, r3);
        addf4(acc, r4); addf4(acc, r5); addf4(acc, r6); addf4(acc, r7);
    }
    if (j + 4 <= end) {                      // unroll-4 middle
        int s0, s1, s2, s3;
        if (LDSE) {
            s0 = es[j]; s1 = es[j + 1]; s2 = es[j + 2]; s3 = es[j + 3];
        } else {
            const int* p = esg + beg0 + j;
            s0 = p[0]; s1 = p[1]; s2 = p[2]; s3 = p[3];
        }
        float4 r0 = hs4[(size_t)s0 * 8 + c8];
        float4 r1 = hs4[(size_t)s1 * 8 + c8];
        float4 r2 = hs4[(size_t)s2 * 8 + c8];
        float4 r3 = hs4[(size_t)s3 * 8 + c8];
        addf4(acc, r0); addf4(acc, r1); addf4(acc, r2); addf4(acc, r3);
        j += 4;
    }
    for (; j < end; ++j) {                   // <=3 singles
        int s0 = LDSE ? es[j] : esg[beg0 + j];
        float4 r0 = hs4[(size_t)s0 * 8 + c8];
        addf4(acc, r0);
    }
}

// ================= K3: aggregate layer1 + gemm2 (fused), 32-node tiles ==============
__global__ __launch_bounds__(256) void agg1_gemm2_kernel(
    const __half* __restrict__ g1, const int* __restrict__ row_ptr,
    const int* __restrict__ esrc, const float* __restrict__ dinv,
    const float* __restrict__ b1, const float* __restrict__ W2,
    __half* __restrict__ g2, int n) {
    __shared__ float Bt[32][68];      // 8704 B
    __shared__ float Ws2[64 * 64];    // 16384 B
    __shared__ int es[ES3];           //  3072 B  -> 28.2KB total, 5 blk/CU cap
    const int t = threadIdx.x, lane = t & 63, wav = t >> 6;
    const int row0 = blockIdx.x * 32;

    const int beg0 = row_ptr[row0];
    const int end0 = row_ptr[min(row0 + 32, n)];
    const int tot = end0 - beg0;
    const bool uselds = (tot <= ES3);
    if (uselds)
        for (int i = t; i < tot; i += 256) es[i] = esrc[beg0 + i];
    __syncthreads();

    {   // W2 -> LDS issued after the barrier so the DMA overlaps aggregation
        const char* gb = (const char*)W2;
        char* lb = (char*)Ws2;
        for (int off = wav * 1024; off < 64 * 64 * 4; off += 4096)
            __builtin_amdgcn_global_load_lds((glob_uint*)(gb + off + lane * 16),
                                             (lds_uint*)(lb + off), 16, 0, 0);
    }

    const int g = t >> 3;        // node in tile (0..31)
    const int c8 = t & 7;        // float4 slot in row
    const int v = row0 + g;
    const float4* __restrict__ hs4 = (const float4*)g1;

    if (v < n) {
        float acc[8];
        {   // self term (g1 pre-scaled by dinv[v])
            float4 raw = hs4[(size_t)v * 8 + c8];
            const __half2* hp = (const __half2*)&raw;
#pragma unroll
            for (int q = 0; q < 4; ++q) {
                float2 f = __half22float2(hp[q]);
                acc[2 * q] = f.x; acc[2 * q + 1] = f.y;
            }
        }
        const int beg = row_ptr[v] - beg0;
        const int end = row_ptr[v + 1] - beg0;
        if (uselds) agg8_body<true>(hs4, es, esrc, beg0, beg, end, c8, acc);
        else        agg8_body<false>(hs4, es, esrc, beg0, beg, end, c8, acc);
        const float dv0 = dinv[v];
        const float* bb = b1 + c8 * 8;
        float4 w0, w1;
        w0.x = fmaxf(fmaf(acc[0], dv0, bb[0]), 0.f);
        w0.y = fmaxf(fmaf(acc[1], dv0, bb[1]), 0.f);
        w0.z = fmaxf(fmaf(acc[2], dv0, bb[2]), 0.f);
        w0.w = fmaxf(fmaf(acc[3], dv0, bb[3]), 0.f);
        w1.x = fmaxf(fmaf(acc[4], dv0, bb[4]), 0.f);
        w1.y = fmaxf(fmaf(acc[5], dv0, bb[5]), 0.f);
        w1.z = fmaxf(fmaf(acc[6], dv0, bb[6]), 0.f);
        w1.w = fmaxf(fmaf(acc[7], dv0, bb[7]), 0.f);
        *(float4*)&Bt[g][c8 * 8] = w0;
        *(float4*)&Bt[g][c8 * 8 + 4] = w1;
    } else {
        *(float4*)&Bt[g][c8 * 8] = make_float4(0.f, 0.f, 0.f, 0.f);
        *(float4*)&Bt[g][c8 * 8 + 4] = make_float4(0.f, 0.f, 0.f, 0.f);
    }
    __syncthreads();

    // gemm2: [32 x 64] @ [64 x 64]; each thread 2 rows x 4 cols
    const int tx = t & 15;
    const int ty = t >> 4;
    float a2[2][4] = {{0.f}};
#pragma unroll 2
    for (int k0 = 0; k0 < 64; k0 += 4) {
        float4 x0 = *(const float4*)&Bt[2 * ty + 0][k0];
        float4 x1 = *(const float4*)&Bt[2 * ty + 1][k0];
        float4 w0 = *(const float4*)&Ws2[(k0 + 0) * 64 + 4 * tx];
        float4 w1 = *(const float4*)&Ws2[(k0 + 1) * 64 + 4 * tx];
        float4 w2 = *(const float4*)&Ws2[(k0 + 2) * 64 + 4 * tx];
        float4 w3 = *(const float4*)&Ws2[(k0 + 3) * 64 + 4 * tx];
        const float* xp[2] = {(const float*)&x0, (const float*)&x1};
        const float* wp[4] = {(const float*)&w0, (const float*)&w1,
                              (const float*)&w2, (const float*)&w3};
#pragma unroll
        for (int r = 0; r < 2; ++r)
#pragma unroll
            for (int kk = 0; kk < 4; ++kk) {
                float av = xp[r][kk];
#pragma unroll
                for (int cc = 0; cc < 4; ++cc)
                    a2[r][cc] = fmaf(av, wp[kk][cc], a2[r][cc]);
            }
    }
#pragma unroll
    for (int r = 0; r < 2; ++r) {
        int row = row0 + 2 * ty + r;
        if (row < n) {
            float dv = dinv[row];
            __half2 p01 = __floats2half2_rn(a2[r][0] * dv, a2[r][1] * dv);
            __half2 p23 = __floats2half2_rn(a2[r][2] * dv, a2[r][3] * dv);
            float2 st;
            ((__half2*)&st)[0] = p01;
            ((__half2*)&st)[1] = p23;
            *(float2*)&g2[(size_t)row * 64 + 4 * tx] = st;
        }
    }
}

// ================= K4: aggregate layer2 -> d_out =================
__global__ __launch_bounds__(256) void aggregate2_kernel(
    const __half* __restrict__ hs,
    const int* __restrict__ row_ptr,
    const int* __restrict__ esrc,
    const float* __restrict__ dinv,
    const float* __restrict__ bias,
    float* __restrict__ out, int n) {
    __shared__ int es[ES4];
    const int t = threadIdx.x;
    const int row0 = blockIdx.x * 32;
    const int beg0 = row_ptr[row0];
    const int end0 = row_ptr[min(row0 + 32, n)];
    const int tot = end0 - beg0;
    const bool uselds = (tot <= ES4);
    if (uselds)
        for (int i = t; i < tot; i += 256) es[i] = esrc[beg0 + i];
    __syncthreads();

    const int v = row0 + (t >> 3);
    if (v >= n) return;
    const int c8 = t & 7;
    const float4* __restrict__ hs4 = (const float4*)hs;

    float acc[8];
    {   // self term (g2 pre-scaled)
        float4 raw = hs4[(size_t)v * 8 + c8];
        const __half2* hp = (const __half2*)&raw;
#pragma unroll
        for (int q = 0; q < 4; ++q) {
            float2 f = __half22float2(hp[q]);
            acc[2 * q] = f.x; acc[2 * q + 1] = f.y;
        }
    }

    const int beg = row_ptr[v] - beg0;
    const int end = row_ptr[v + 1] - beg0;
    if (uselds) agg8_body<true>(hs4, es, esrc, beg0, beg, end, c8, acc);
    else        agg8_body<false>(hs4, es, esrc, beg0, beg, end, c8, acc);

    float dv = dinv[v];
    float4 b0 = *(const float4*)(bias + c8 * 8);
    float4 b1v = *(const float4*)(bias + c8 * 8 + 4);
    float4 o0, o1;
    o0.x = fmaf(acc[0], dv, b0.x); o0.y = fmaf(acc[1], dv, b0.y);
    o0.z = fmaf(acc[2], dv, b0.z); o0.w = fmaf(acc[3], dv, b0.w);
    o1.x = fmaf(acc[4], dv, b1v.x); o1.y = fmaf(acc[5], dv, b1v.y);
    o1.z = fmaf(acc[6], dv, b1v.z); o1.w = fmaf(acc[7], dv, b1v.w);
    float4* op = (float4*)(out + (size_t)v * 64 + c8 * 8);
    op[0] = o0;
    op[1] = o1;
}

extern "C" void kernel_launch(void* const* d_in, const int* in_sizes, int n_in,
                              void* d_out, int out_size, void* d_ws, size_t ws_size,
                              hipStream_t stream) {
    const float* x  = (const float*)d_in[0];
    const int*   ei = (const int*)d_in[1];
    const float* W1 = (const float*)d_in[2];
    const float* b1 = (const float*)d_in[3];
    const float* W2 = (const float*)d_in[4];
    const float* b2 = (const float*)d_in[5];
    float* out = (float*)d_out;

    const int C_IN = 128;
    const int n = in_sizes[0] / C_IN;   // 50000 (<= 65536: nb <= 1024)
    const int E = in_sizes[1] / 2;      // 800000
    const int* src = ei;
    const int* dst = ei + E;

    const int nb = (n + 63) >> 6;               // 782 buckets of 64 nodes
    const int ngb = (n + 63) / 64;              // gemm1 tile blocks
    const int n32 = (n + 31) / 32;              // 32-node tiles for K3/K4
    const int ePer = (E + NCHUNK - 1) / NCHUNK; // edges per hist/scatter chunk

    // Workspace: dinv | g1 | g2 | row_ptr | S | T | ebuf | esrc | W1h
    char* w = (char*)d_ws;
    float*    dinv    = (float*)w;    w += alignup((size_t)n * sizeof(float));
    __half*   g1      = (__half*)w;   w += alignup((size_t)n * C_HID * sizeof(__half));
    __half*   g2      = (__half*)w;   w += alignup((size_t)n * C_HID * sizeof(__half));
    int*      row_ptr = (int*)w;      w += alignup((size_t)(n + 1) * sizeof(int));
    int*      S       = (int*)w;      w += alignup((size_t)nb * NCHUNK * sizeof(int));
    int*      T       = (int*)w;      w += alignup((size_t)(nb + 1) * sizeof(int));
    unsigned* ebuf    = (unsigned*)w; w += alignup((size_t)E * sizeof(unsigned));
    int*      esrc    = (int*)w;      w += alignup((size_t)E * sizeof(int));
    __half*   W1h     = (__half*)w;

    // K0: W1 -> fp16 transposed+swizzled (8192 elems)
    cvt_w1t_kernel<<<32, 256, 0, stream>>>(W1, W1h);

    // K1: gemm1 (MFMA) || hist
    gemm1_hist_kernel<128><<<NCHUNK + ngb, 256, 0, stream>>>(
        x, W1h, dst, g1, S, n, E, ePer, nb);

    // K2: CSR build
    scan_rows_kernel<<<nb, 256, 0, stream>>>(S, T);
    scatter_kernel<<<NCHUNK, 256, 0, stream>>>(src, dst, E, ePer, S, T, ebuf, nb);
    build_kernel<<<nb, 256, 0, stream>>>(ebuf, T, row_ptr, dinv, esrc, g1, n, nb);

    // K3: aggregate layer1 + gemm2 fused (32-node tiles)
    agg1_gemm2_kernel<<<n32, 256, 0, stream>>>(
        g1, row_ptr, esrc, dinv, b1, W2, g2, n);

    // K4: aggregate layer2 -> out (32-node tiles)
    aggregate2_kernel<<<n32, 256, 0, stream>>>(
        g2, row_ptr, esrc, dinv, b2, out, n);
}